// Round 1
// baseline (46308.508 us; speedup 1.0000x reference)
//
#include <hip/hip_runtime.h>
#include <stdint.h>

#define T_LEN 4096
#define NVOC 256
#define EMBD 512
#define HID 512
#define G4 2048
#define NEGV (-10000.0f)
#define START_TAG 0
#define STOP_TAG 1
#define NPROD 32   // workgroups per LSTM direction

struct __align__(128) Slab {
    float h[16];
    unsigned int flag;
    unsigned int pad[15];
};
static_assert(sizeof(Slab) == 128, "slab size");

// ---------------- generic C[M,N] = A[M,K] @ B[N,K]^T + bias0 + bias1 ----------------
__global__ __launch_bounds__(256) void gemm_abt(
    const float* __restrict__ A, const float* __restrict__ B,
    const float* __restrict__ bias0, const float* __restrict__ bias1,
    float* __restrict__ C, int M, int N, int K)
{
    __shared__ float As[16][65];
    __shared__ float Bs[16][65];
    int m0 = blockIdx.x * 64, n0 = blockIdx.y * 64;
    int tid = threadIdx.x;
    int lr = tid >> 2;          // 0..63
    int lk = (tid & 3) << 2;    // 0,4,8,12
    int tr = tid & 15, tc = tid >> 4;
    float acc[4][4] = {};
    for (int k0 = 0; k0 < K; k0 += 16) {
        float4 av = *(const float4*)(A + (size_t)(m0 + lr) * K + k0 + lk);
        float4 bv = *(const float4*)(B + (size_t)(n0 + lr) * K + k0 + lk);
        As[lk + 0][lr] = av.x; As[lk + 1][lr] = av.y; As[lk + 2][lr] = av.z; As[lk + 3][lr] = av.w;
        Bs[lk + 0][lr] = bv.x; Bs[lk + 1][lr] = bv.y; Bs[lk + 2][lr] = bv.z; Bs[lk + 3][lr] = bv.w;
        __syncthreads();
#pragma unroll
        for (int kk = 0; kk < 16; ++kk) {
            float a[4], b[4];
#pragma unroll
            for (int x = 0; x < 4; ++x) a[x] = As[kk][tr * 4 + x];
#pragma unroll
            for (int y = 0; y < 4; ++y) b[y] = Bs[kk][tc * 4 + y];
#pragma unroll
            for (int y = 0; y < 4; ++y)
#pragma unroll
                for (int x = 0; x < 4; ++x)
                    acc[y][x] += a[x] * b[y];
        }
        __syncthreads();
    }
#pragma unroll
    for (int y = 0; y < 4; ++y) {
        int n = n0 + tc * 4 + y;
        float bb = bias0 ? bias0[n] : 0.f;
        if (bias1) bb += bias1[n];
#pragma unroll
        for (int x = 0; x < 4; ++x)
            C[(size_t)(m0 + tr * 4 + x) * N + n] = acc[y][x] + bb;
    }
}

// ---------------- persistent BiLSTM ----------------
// 64 blocks x 256 threads. blocks 0..31: forward, 32..63: backward.
// Each WG owns 16 hidden units; W_hh slice (64 rows x 512) lives in VGPRs.
__global__ __launch_bounds__(256) void lstm_kernel(
    const int* __restrict__ src,
    const float* __restrict__ PE_f, const float* __restrict__ PE_b,
    const float* __restrict__ Whh_f, const float* __restrict__ Whh_b,
    float* __restrict__ H, Slab* slabs)
{
    int wg  = blockIdx.x & 31;
    int dir = blockIdx.x >> 5;          // 0 = fwd, 1 = bwd
    const float* PE  = dir ? PE_b : PE_f;
    const float* Whh = dir ? Whh_b : Whh_f;
    Slab* myslabs = slabs + (size_t)dir * 2 * NPROD;   // [slot][k]

    int tid = threadIdx.x;
    int r = tid >> 2, q = tid & 3;      // row 0..63, column quarter 0..3
    int g = r >> 4, u = r & 15;         // gate, unit
    int hu0 = wg * 16;
    int grow = g * 512 + hu0 + u;       // global gate row

    // weights -> registers (32 float4 = 128 VGPR)
    float4 w4[32];
    const float4* wsrc = (const float4*)(Whh + (size_t)grow * 512 + q * 128);
#pragma unroll
    for (int j = 0; j < 32; ++j) w4[j] = wsrc[j];

    __shared__ __align__(16) float h_sh[512];
    __shared__ float gate_sh[64];
    float c_state = 0.f;                // valid for tid < 16
    float4 zero4 = make_float4(0.f, 0.f, 0.f, 0.f);

    for (int s = 0; s < T_LEN; ++s) {
        int t = dir ? (T_LEN - 1 - s) : s;
        int st = src[t];
        float pe0 = 0.f, pe1 = 0.f, pe2 = 0.f, pe3 = 0.f;
        if (tid < 16) {                  // prefetch input-projection rows early
            const float* pb2 = PE + (size_t)st * G4 + hu0 + tid;
            pe0 = pb2[0]; pe1 = pb2[512]; pe2 = pb2[1024]; pe3 = pb2[1536];
        }
        if (s == 0) {
            if (tid < 128) ((float4*)h_sh)[tid] = zero4;
            __syncthreads();
        } else {
            int slot = (s - 1) & 1;
            if (tid < NPROD) {
                unsigned int* fp = &myslabs[slot * NPROD + tid].flag;
                while (__hip_atomic_load(fp, __ATOMIC_RELAXED, __HIP_MEMORY_SCOPE_AGENT) < (unsigned)s)
                    __builtin_amdgcn_s_sleep(1);
            }
            __syncthreads();
            __threadfence();            // acquire: invalidate stale cached lines
            int k = tid >> 3, e = (tid & 7) << 1;
            float2 hv = *(const float2*)(myslabs[slot * NPROD + k].h + e);
            *(float2*)(h_sh + k * 16 + e) = hv;
            __syncthreads();
        }
        // 128-wide partial dot (columns q*128 .. q*128+127)
        float a0 = 0.f, a1 = 0.f, a2 = 0.f, a3 = 0.f;
        const float4* hq = (const float4*)(h_sh + q * 128);
#pragma unroll
        for (int j = 0; j < 32; ++j) {
            float4 hv = hq[j];
            a0 += w4[j].x * hv.x; a1 += w4[j].y * hv.y;
            a2 += w4[j].z * hv.z; a3 += w4[j].w * hv.w;
        }
        float dot = (a0 + a1) + (a2 + a3);
        dot += __shfl_xor(dot, 1);
        dot += __shfl_xor(dot, 2);
        if (q == 0) gate_sh[r] = dot;
        __syncthreads();
        if (tid < 16) {
            float gi = gate_sh[tid]      + pe0;
            float gf = gate_sh[16 + tid] + pe1;
            float gg = gate_sh[32 + tid] + pe2;
            float go = gate_sh[48 + tid] + pe3;
            float si = 1.f / (1.f + __expf(-gi));
            float sf = 1.f / (1.f + __expf(-gf));
            float so = 1.f / (1.f + __expf(-go));
            float tg = tanhf(gg);
            c_state = sf * c_state + si * tg;
            float hval = so * tanhf(c_state);
            myslabs[(s & 1) * NPROD + wg].h[tid] = hval;
            H[(size_t)t * 1024 + dir * 512 + hu0 + tid] = hval;
        }
        __syncthreads();
        __threadfence();                // release: push h slice to coherence point
        if (tid == 0)
            __hip_atomic_store(&myslabs[(s & 1) * NPROD + wg].flag, (unsigned)(s + 1),
                               __ATOMIC_RELEASE, __HIP_MEMORY_SCOPE_AGENT);
    }
}

// ---------------- Viterbi forward: max-only, single WG, trans in VGPRs ----------------
__global__ __launch_bounds__(1024) void viterbi_fwd_kernel(
    const float* __restrict__ feats, const float* __restrict__ trans,
    float* __restrict__ fv_all)
{
    __shared__ float fv[2][256];
    __shared__ float red[4][256];
    int tid = threadIdx.x;
    int j = tid & 255, q = tid >> 8;
    float4 Tr[16];
#pragma unroll
    for (int b = 0; b < 16; ++b)
        Tr[b] = *(const float4*)(trans + (size_t)j * 256 + q * 64 + b * 4);
    if (tid < 256) fv[0][tid] = (tid == START_TAG) ? 0.f : NEGV;
    __syncthreads();
    int p = 0;
    for (int t = 0; t < T_LEN; ++t) {
        float ft = 0.f;
        if (q == 0) ft = feats[(size_t)t * 256 + j];
        float m = -1e30f;
#pragma unroll
        for (int b = 0; b < 16; ++b) {
            float4 f4 = *(const float4*)(&fv[p][q * 64 + b * 4]);
            float s0 = f4.x + Tr[b].x, s1 = f4.y + Tr[b].y;
            float s2 = f4.z + Tr[b].z, s3 = f4.w + Tr[b].w;
            m = fmaxf(m, fmaxf(s0, s1));
            m = fmaxf(m, fmaxf(s2, s3));
        }
        red[q][j] = m;
        __syncthreads();
        if (tid < 256) {
            float mm = fmaxf(fmaxf(red[0][j], red[1][j]), fmaxf(red[2][j], red[3][j]));
            float v = mm + ft;
            fv[p ^ 1][j] = v;
            fv_all[(size_t)t * 256 + j] = v;
        }
        __syncthreads();
        p ^= 1;
    }
}

// ---------------- backpointers, recomputed fully parallel ----------------
__global__ __launch_bounds__(256) void bp_kernel(
    const float* __restrict__ fv_all, const float* __restrict__ trans,
    unsigned char* __restrict__ bp)
{
    __shared__ float fp[256];
    int t = blockIdx.x;
    int j = threadIdx.x;
    fp[j] = (t == 0) ? ((j == START_TAG) ? 0.f : NEGV)
                     : fv_all[(size_t)(t - 1) * 256 + j];
    __syncthreads();
    const float* Trow = trans + (size_t)j * 256;
    float m = -1e30f; int mi = 0;
    for (int i = 0; i < 256; ++i) {
        float s = fp[i] + Trow[i];
        if (s > m) { m = s; mi = i; }   // strict > : first max index (jnp.argmax)
    }
    bp[(size_t)t * 256 + j] = (unsigned char)mi;
}

// ---------------- segmented backtrace: per-segment tag-map evolution ----------------
__global__ __launch_bounds__(256) void evol_kernel(
    const unsigned char* __restrict__ bp, unsigned char* __restrict__ evol)
{
    __shared__ unsigned char tm[256];
    __shared__ unsigned char row[256];
    int s = blockIdx.x;
    int tid = threadIdx.x;
    int t_top = s * 64 + 63;
    tm[tid] = (unsigned char)tid;
    evol[(size_t)t_top * 256 + tid] = (unsigned char)tid;
    __syncthreads();
    for (int t = t_top - 1; t >= s * 64; --t) {
        row[tid] = bp[(size_t)(t + 1) * 256 + tid];
        __syncthreads();
        unsigned char nt = row[tm[tid]];
        tm[tid] = nt;
        evol[(size_t)t * 256 + tid] = nt;
        __syncthreads();
    }
}

__global__ __launch_bounds__(256) void finalize_kernel(
    const float* __restrict__ fv_all, const float* __restrict__ trans,
    const unsigned char* __restrict__ bp, const unsigned char* __restrict__ evol,
    float* __restrict__ out)
{
    __shared__ float term[256];
    __shared__ unsigned char top[64];
    int tid = threadIdx.x;
    term[tid] = fv_all[(size_t)(T_LEN - 1) * 256 + tid] + trans[STOP_TAG * 256 + tid];
    __syncthreads();
    if (tid == 0) {
        float m = term[0]; int best = 0;
        for (int i = 1; i < 256; ++i) if (term[i] > m) { m = term[i]; best = i; }
        out[0] = m;
        int tag = best;
        top[63] = (unsigned char)tag;
        for (int s2 = 63; s2 >= 1; --s2) {
            int tb = s2 * 64;
            int pb = evol[(size_t)tb * 256 + tag];     // path[s2*64]
            tag = bp[(size_t)tb * 256 + pb];           // path[s2*64 - 1]
            top[s2 - 1] = (unsigned char)tag;
        }
    }
    __syncthreads();
    for (int t = tid; t < T_LEN; t += 256)
        out[1 + t] = (float)evol[(size_t)t * 256 + top[t >> 6]];
}

// ---------------- host launcher ----------------
extern "C" void kernel_launch(void* const* d_in, const int* in_sizes, int n_in,
                              void* d_out, int out_size, void* d_ws, size_t ws_size,
                              hipStream_t stream)
{
    const int*   src     = (const int*)d_in[0];
    const float* emb     = (const float*)d_in[2];
    const float* W_ih_f  = (const float*)d_in[3];
    const float* W_hh_f  = (const float*)d_in[4];
    const float* b_ih_f  = (const float*)d_in[5];
    const float* b_hh_f  = (const float*)d_in[6];
    const float* W_ih_b  = (const float*)d_in[7];
    const float* W_hh_b  = (const float*)d_in[8];
    const float* b_ih_b  = (const float*)d_in[9];
    const float* b_hh_b  = (const float*)d_in[10];
    const float* W_tag   = (const float*)d_in[11];
    const float* b_tag   = (const float*)d_in[12];
    const float* trans   = (const float*)d_in[13];
    float* out = (float*)d_out;

    char* w = (char*)d_ws;
    Slab* slabs = (Slab*)w;
    size_t off = 16384;
    float* PE_f = (float*)(w + off); off += (size_t)NVOC * G4 * 4;
    float* PE_b = (float*)(w + off); off += (size_t)NVOC * G4 * 4;
    float* H    = (float*)(w + off); off += (size_t)T_LEN * 1024 * 4;
    float* feats= (float*)(w + off); off += (size_t)T_LEN * 256 * 4;
    float* fv   = (float*)(w + off); off += (size_t)T_LEN * 256 * 4;
    unsigned char* bp   = (unsigned char*)(w + off); off += (size_t)T_LEN * 256;
    unsigned char* evol = (unsigned char*)(w + off); off += (size_t)T_LEN * 256;

    hipMemsetAsync(slabs, 0, 16384, stream);

    // PE = embedding @ W_ih^T + b_ih + b_hh   (256 x 2048)
    gemm_abt<<<dim3(NVOC / 64, G4 / 64), 256, 0, stream>>>(emb, W_ih_f, b_ih_f, b_hh_f, PE_f, NVOC, G4, EMBD);
    gemm_abt<<<dim3(NVOC / 64, G4 / 64), 256, 0, stream>>>(emb, W_ih_b, b_ih_b, b_hh_b, PE_b, NVOC, G4, EMBD);

    lstm_kernel<<<64, 256, 0, stream>>>(src, PE_f, PE_b, W_hh_f, W_hh_b, H, slabs);

    // feats = H @ W_tag^T + b_tag   (4096 x 256)
    gemm_abt<<<dim3(T_LEN / 64, 256 / 64), 256, 0, stream>>>(H, W_tag, b_tag, nullptr, feats, T_LEN, 256, 1024);

    viterbi_fwd_kernel<<<1, 1024, 0, stream>>>(feats, trans, fv);
    bp_kernel<<<T_LEN, 256, 0, stream>>>(fv, trans, bp);
    evol_kernel<<<T_LEN / 64, 256, 0, stream>>>(bp, evol);
    finalize_kernel<<<1, 256, 0, stream>>>(fv, trans, bp, evol, out);
}

// Round 2
// 10879.732 us; speedup vs baseline: 4.2564x; 4.2564x over previous
//
#include <hip/hip_runtime.h>
#include <stdint.h>

#define T_LEN 4096
#define NVOC 256
#define EMBD 512
#define HID 512
#define G4 2048
#define NEGV (-10000.0f)
#define START_TAG 0
#define STOP_TAG 1
#define NPROD 32   // workgroups per LSTM direction

// ---------------- generic C[M,N] = A[M,K] @ B[N,K]^T + bias0 + bias1 ----------------
__global__ __launch_bounds__(256) void gemm_abt(
    const float* __restrict__ A, const float* __restrict__ B,
    const float* __restrict__ bias0, const float* __restrict__ bias1,
    float* __restrict__ C, int M, int N, int K)
{
    __shared__ float As[16][65];
    __shared__ float Bs[16][65];
    int m0 = blockIdx.x * 64, n0 = blockIdx.y * 64;
    int tid = threadIdx.x;
    int lr = tid >> 2;          // 0..63
    int lk = (tid & 3) << 2;    // 0,4,8,12
    int tr = tid & 15, tc = tid >> 4;
    float acc[4][4] = {};
    for (int k0 = 0; k0 < K; k0 += 16) {
        float4 av = *(const float4*)(A + (size_t)(m0 + lr) * K + k0 + lk);
        float4 bv = *(const float4*)(B + (size_t)(n0 + lr) * K + k0 + lk);
        As[lk + 0][lr] = av.x; As[lk + 1][lr] = av.y; As[lk + 2][lr] = av.z; As[lk + 3][lr] = av.w;
        Bs[lk + 0][lr] = bv.x; Bs[lk + 1][lr] = bv.y; Bs[lk + 2][lr] = bv.z; Bs[lk + 3][lr] = bv.w;
        __syncthreads();
#pragma unroll
        for (int kk = 0; kk < 16; ++kk) {
            float a[4], b[4];
#pragma unroll
            for (int x = 0; x < 4; ++x) a[x] = As[kk][tr * 4 + x];
#pragma unroll
            for (int y = 0; y < 4; ++y) b[y] = Bs[kk][tc * 4 + y];
#pragma unroll
            for (int y = 0; y < 4; ++y)
#pragma unroll
                for (int x = 0; x < 4; ++x)
                    acc[y][x] += a[x] * b[y];
        }
        __syncthreads();
    }
#pragma unroll
    for (int y = 0; y < 4; ++y) {
        int n = n0 + tc * 4 + y;
        float bb = bias0 ? bias0[n] : 0.f;
        if (bias1) bb += bias1[n];
#pragma unroll
        for (int x = 0; x < 4; ++x)
            C[(size_t)(m0 + tr * 4 + x) * N + n] = acc[y][x] + bb;
    }
}

__device__ __forceinline__ float fast_sig(float x) {
    return __builtin_amdgcn_rcpf(1.f + __expf(-x));
}
__device__ __forceinline__ float fast_tanh(float x) {
    // tanh(x) = 2*sigmoid(2x) - 1
    return 2.f * __builtin_amdgcn_rcpf(1.f + __expf(-2.f * x)) - 1.f;
}

// ---------------- persistent BiLSTM, fence-free tagged-word exchange ----------------
// 64 blocks x 256 threads. blocks 0..31: forward, 32..63: backward.
// Each WG owns 16 hidden units; W_hh slice (64 rows x 512) lives in VGPRs.
// h exchange: each element published as one 64-bit word (tag<<32)|bits(float),
// relaxed agent-scope atomics -> value+tag single-copy atomic, NO fences.
// pub layout: [dir][slot(=step&1)][512] uint64.
__global__ __launch_bounds__(256) void lstm_kernel(
    const int* __restrict__ src,
    const float* __restrict__ PE_f, const float* __restrict__ PE_b,
    const float* __restrict__ Whh_f, const float* __restrict__ Whh_b,
    float* __restrict__ H, unsigned long long* __restrict__ pub)
{
    int wg  = blockIdx.x & 31;
    int dir = blockIdx.x >> 5;          // 0 = fwd, 1 = bwd
    const float* PE  = dir ? PE_b : PE_f;
    const float* Whh = dir ? Whh_b : Whh_f;
    unsigned long long* mypub = pub + (size_t)dir * 1024;   // [slot][512]

    int tid = threadIdx.x;
    int r = tid >> 2, q = tid & 3;      // row 0..63, column quarter 0..3
    int g = r >> 4, u = r & 15;         // gate, unit
    int hu0 = wg * 16;
    int grow = g * 512 + hu0 + u;       // global gate row

    // weights -> registers (32 float4 = 128 VGPR)
    float4 w4[32];
    const float4* wsrc = (const float4*)(Whh + (size_t)grow * 512 + q * 128);
#pragma unroll
    for (int j = 0; j < 32; ++j) w4[j] = wsrc[j];

    // padded: quarter stride 132 floats -> q-chunks land on distinct banks
    __shared__ __align__(16) float h_sh[4][132];
    __shared__ float gate_sh[64];
    float c_state = 0.f;                // valid for tid < 16

    int e0 = tid * 2;                   // this thread polls elements e0, e0+1
    int pq = e0 >> 7, pj = e0 & 127;

    for (int s = 0; s < T_LEN; ++s) {
        int t = dir ? (T_LEN - 1 - s) : s;
        int st = src[t];
        float pe0 = 0.f, pe1 = 0.f, pe2 = 0.f, pe3 = 0.f;
        if (tid < 16) {                  // prefetch input-projection rows early
            const float* pb2 = PE + (size_t)st * G4 + hu0 + tid;
            pe0 = pb2[0]; pe1 = pb2[512]; pe2 = pb2[1024]; pe3 = pb2[1536];
        }
        if (s == 0) {
            h_sh[pq][pj] = 0.f; h_sh[pq][pj + 1] = 0.f;
        } else {
            unsigned long long* p0 = mypub + (size_t)((s - 1) & 1) * 512 + e0;
            unsigned int want = (unsigned)s;
            unsigned long long w0 = __hip_atomic_load(p0, __ATOMIC_RELAXED, __HIP_MEMORY_SCOPE_AGENT);
            while ((unsigned)(w0 >> 32) < want) {
                __builtin_amdgcn_s_sleep(1);
                w0 = __hip_atomic_load(p0, __ATOMIC_RELAXED, __HIP_MEMORY_SCOPE_AGENT);
            }
            unsigned long long w1 = __hip_atomic_load(p0 + 1, __ATOMIC_RELAXED, __HIP_MEMORY_SCOPE_AGENT);
            while ((unsigned)(w1 >> 32) < want) {
                __builtin_amdgcn_s_sleep(1);
                w1 = __hip_atomic_load(p0 + 1, __ATOMIC_RELAXED, __HIP_MEMORY_SCOPE_AGENT);
            }
            __builtin_memcpy(&h_sh[pq][pj], &w0, 4);       // low 32 bits = float
            __builtin_memcpy(&h_sh[pq][pj + 1], &w1, 4);
        }
        __syncthreads();                 // [A] h_sh ready

        // 128-wide partial dot (columns q*128 .. q*128+127)
        float a0 = 0.f, a1 = 0.f, a2 = 0.f, a3 = 0.f;
        const float4* hq = (const float4*)(&h_sh[q][0]);
#pragma unroll
        for (int j = 0; j < 32; ++j) {
            float4 hv = hq[j];
            a0 += w4[j].x * hv.x; a1 += w4[j].y * hv.y;
            a2 += w4[j].z * hv.z; a3 += w4[j].w * hv.w;
        }
        float dot = (a0 + a1) + (a2 + a3);
        dot += __shfl_xor(dot, 1);
        dot += __shfl_xor(dot, 2);
        if (q == 0) gate_sh[r] = dot;
        __syncthreads();                 // [B] gates ready; h_sh free to overwrite

        if (tid < 16) {
            float gi = gate_sh[tid]      + pe0;
            float gf = gate_sh[16 + tid] + pe1;
            float gg = gate_sh[32 + tid] + pe2;
            float go = gate_sh[48 + tid] + pe3;
            float si = fast_sig(gi);
            float sf = fast_sig(gf);
            float so = fast_sig(go);
            float tg = fast_tanh(gg);
            c_state = sf * c_state + si * tg;
            float hval = so * fast_tanh(c_state);
            unsigned int hb; __builtin_memcpy(&hb, &hval, 4);
            unsigned long long w = ((unsigned long long)(unsigned)(s + 1) << 32) | (unsigned long long)hb;
            __hip_atomic_store(mypub + (size_t)(s & 1) * 512 + hu0 + tid, w,
                               __ATOMIC_RELAXED, __HIP_MEMORY_SCOPE_AGENT);
            H[(size_t)t * 1024 + dir * 512 + hu0 + tid] = hval;
        }
        // no barrier needed: next-step h_sh writes are gated by [B] (writers
        // passed it) and gate_sh readers finish before next [A] admits writers.
    }
}

// ---------------- Viterbi forward: max-only, single WG, trans in VGPRs ----------------
__global__ __launch_bounds__(1024) void viterbi_fwd_kernel(
    const float* __restrict__ feats, const float* __restrict__ trans,
    float* __restrict__ fv_all)
{
    __shared__ float fv[2][256];
    __shared__ float red[4][256];
    int tid = threadIdx.x;
    int j = tid & 255, q = tid >> 8;
    float4 Tr[16];
#pragma unroll
    for (int b = 0; b < 16; ++b)
        Tr[b] = *(const float4*)(trans + (size_t)j * 256 + q * 64 + b * 4);
    if (tid < 256) fv[0][tid] = (tid == START_TAG) ? 0.f : NEGV;
    __syncthreads();
    int p = 0;
    for (int t = 0; t < T_LEN; ++t) {
        float ft = 0.f;
        if (q == 0) ft = feats[(size_t)t * 256 + j];
        float m = -1e30f;
#pragma unroll
        for (int b = 0; b < 16; ++b) {
            float4 f4 = *(const float4*)(&fv[p][q * 64 + b * 4]);
            float s0 = f4.x + Tr[b].x, s1 = f4.y + Tr[b].y;
            float s2 = f4.z + Tr[b].z, s3 = f4.w + Tr[b].w;
            m = fmaxf(m, fmaxf(s0, s1));
            m = fmaxf(m, fmaxf(s2, s3));
        }
        red[q][j] = m;
        __syncthreads();
        if (tid < 256) {
            float mm = fmaxf(fmaxf(red[0][j], red[1][j]), fmaxf(red[2][j], red[3][j]));
            float v = mm + ft;
            fv[p ^ 1][j] = v;
            fv_all[(size_t)t * 256 + j] = v;
        }
        __syncthreads();
        p ^= 1;
    }
}

// ---------------- backpointers, recomputed fully parallel ----------------
__global__ __launch_bounds__(256) void bp_kernel(
    const float* __restrict__ fv_all, const float* __restrict__ trans,
    unsigned char* __restrict__ bp)
{
    __shared__ float fp[256];
    int t = blockIdx.x;
    int j = threadIdx.x;
    fp[j] = (t == 0) ? ((j == START_TAG) ? 0.f : NEGV)
                     : fv_all[(size_t)(t - 1) * 256 + j];
    __syncthreads();
    const float* Trow = trans + (size_t)j * 256;
    float m = -1e30f; int mi = 0;
    for (int i = 0; i < 256; ++i) {
        float s = fp[i] + Trow[i];
        if (s > m) { m = s; mi = i; }   // strict > : first max index (jnp.argmax)
    }
    bp[(size_t)t * 256 + j] = (unsigned char)mi;
}

// ---------------- segmented backtrace: per-segment tag-map evolution ----------------
__global__ __launch_bounds__(256) void evol_kernel(
    const unsigned char* __restrict__ bp, unsigned char* __restrict__ evol)
{
    __shared__ unsigned char tm[256];
    __shared__ unsigned char row[256];
    int s = blockIdx.x;
    int tid = threadIdx.x;
    int t_top = s * 64 + 63;
    tm[tid] = (unsigned char)tid;
    evol[(size_t)t_top * 256 + tid] = (unsigned char)tid;
    __syncthreads();
    for (int t = t_top - 1; t >= s * 64; --t) {
        row[tid] = bp[(size_t)(t + 1) * 256 + tid];
        __syncthreads();
        unsigned char nt = row[tm[tid]];
        tm[tid] = nt;
        evol[(size_t)t * 256 + tid] = nt;
        __syncthreads();
    }
}

__global__ __launch_bounds__(256) void finalize_kernel(
    const float* __restrict__ fv_all, const float* __restrict__ trans,
    const unsigned char* __restrict__ bp, const unsigned char* __restrict__ evol,
    float* __restrict__ out)
{
    __shared__ float term[256];
    __shared__ unsigned char top[64];
    int tid = threadIdx.x;
    term[tid] = fv_all[(size_t)(T_LEN - 1) * 256 + tid] + trans[STOP_TAG * 256 + tid];
    __syncthreads();
    if (tid == 0) {
        float m = term[0]; int best = 0;
        for (int i = 1; i < 256; ++i) if (term[i] > m) { m = term[i]; best = i; }
        out[0] = m;
        int tag = best;
        top[63] = (unsigned char)tag;
        for (int s2 = 63; s2 >= 1; --s2) {
            int tb = s2 * 64;
            int pb = evol[(size_t)tb * 256 + tag];     // path[s2*64]
            tag = bp[(size_t)tb * 256 + pb];           // path[s2*64 - 1]
            top[s2 - 1] = (unsigned char)tag;
        }
    }
    __syncthreads();
    for (int t = tid; t < T_LEN; t += 256)
        out[1 + t] = (float)evol[(size_t)t * 256 + top[t >> 6]];
}

// ---------------- host launcher ----------------
extern "C" void kernel_launch(void* const* d_in, const int* in_sizes, int n_in,
                              void* d_out, int out_size, void* d_ws, size_t ws_size,
                              hipStream_t stream)
{
    const int*   src     = (const int*)d_in[0];
    const float* emb     = (const float*)d_in[2];
    const float* W_ih_f  = (const float*)d_in[3];
    const float* W_hh_f  = (const float*)d_in[4];
    const float* b_ih_f  = (const float*)d_in[5];
    const float* b_hh_f  = (const float*)d_in[6];
    const float* W_ih_b  = (const float*)d_in[7];
    const float* W_hh_b  = (const float*)d_in[8];
    const float* b_ih_b  = (const float*)d_in[9];
    const float* b_hh_b  = (const float*)d_in[10];
    const float* W_tag   = (const float*)d_in[11];
    const float* b_tag   = (const float*)d_in[12];
    const float* trans   = (const float*)d_in[13];
    float* out = (float*)d_out;

    char* w = (char*)d_ws;
    unsigned long long* pub = (unsigned long long*)w;   // 2 dir x 2 slot x 512 x 8B = 16 KB
    size_t off = 16384;
    float* PE_f = (float*)(w + off); off += (size_t)NVOC * G4 * 4;
    float* PE_b = (float*)(w + off); off += (size_t)NVOC * G4 * 4;
    float* H    = (float*)(w + off); off += (size_t)T_LEN * 1024 * 4;
    float* feats= (float*)(w + off); off += (size_t)T_LEN * 256 * 4;
    float* fv   = (float*)(w + off); off += (size_t)T_LEN * 256 * 4;
    unsigned char* bp   = (unsigned char*)(w + off); off += (size_t)T_LEN * 256;
    unsigned char* evol = (unsigned char*)(w + off); off += (size_t)T_LEN * 256;

    hipMemsetAsync(pub, 0, 16384, stream);

    // PE = embedding @ W_ih^T + b_ih + b_hh   (256 x 2048)
    gemm_abt<<<dim3(NVOC / 64, G4 / 64), 256, 0, stream>>>(emb, W_ih_f, b_ih_f, b_hh_f, PE_f, NVOC, G4, EMBD);
    gemm_abt<<<dim3(NVOC / 64, G4 / 64), 256, 0, stream>>>(emb, W_ih_b, b_ih_b, b_hh_b, PE_b, NVOC, G4, EMBD);

    lstm_kernel<<<64, 256, 0, stream>>>(src, PE_f, PE_b, W_hh_f, W_hh_b, H, pub);

    // feats = H @ W_tag^T + b_tag   (4096 x 256)
    gemm_abt<<<dim3(T_LEN / 64, 256 / 64), 256, 0, stream>>>(H, W_tag, b_tag, nullptr, feats, T_LEN, 256, 1024);

    viterbi_fwd_kernel<<<1, 1024, 0, stream>>>(feats, trans, fv);
    bp_kernel<<<T_LEN, 256, 0, stream>>>(fv, trans, bp);
    evol_kernel<<<T_LEN / 64, 256, 0, stream>>>(bp, evol);
    finalize_kernel<<<1, 256, 0, stream>>>(fv, trans, bp, evol, out);
}